// Round 2
// baseline (941.343 us; speedup 1.0000x reference)
//
#include <hip/hip_runtime.h>
#include <hip/hip_bf16.h>

typedef __attribute__((ext_vector_type(4))) float f32x4;
typedef __bf16 bf16x8 __attribute__((ext_vector_type(8)));

#define TOKENS 16384
#define DIM    2048
#define NKVQ   3072

__device__ __forceinline__ void gload_lds16(const void* g, void* l) {
  __builtin_amdgcn_global_load_lds((const __attribute__((address_space(1))) void*)g,
                                   (__attribute__((address_space(3))) void*)l, 16, 0, 0);
}

__device__ __forceinline__ unsigned short bfbits(float x) {
  __bf16 b = (__bf16)x; return __builtin_bit_cast(unsigned short, b);
}
__device__ __forceinline__ float bff(unsigned short u) {
  return (float)__builtin_bit_cast(__bf16, u);
}

// ---------------- cast fp32 -> bf16, 8 elems/thread ----------------
__global__ void cast8_kernel(const float* __restrict__ src, __bf16* __restrict__ dst, int n8) {
  int i = blockIdx.x * blockDim.x + threadIdx.x;
  if (i >= n8) return;
  const float4* s = (const float4*)src;
  float4 a = s[2 * i], b = s[2 * i + 1];
  bf16x8 o;
  o[0] = (__bf16)a.x; o[1] = (__bf16)a.y; o[2] = (__bf16)a.z; o[3] = (__bf16)a.w;
  o[4] = (__bf16)b.x; o[5] = (__bf16)b.y; o[6] = (__bf16)b.z; o[7] = (__bf16)b.w;
  ((bf16x8*)dst)[i] = o;
}

// ---------------- Weff[d, h*64+k] = sum_v Wo[d, h*64+v] * mem[h,k,v] ----------------
__global__ void weff_kernel(const float* __restrict__ Wo, const float* __restrict__ mem,
                            __bf16* __restrict__ Weff) {
  int idx = blockIdx.x * blockDim.x + threadIdx.x;  // 2048*1024
  int d = idx >> 10, hk = idx & 1023, h = hk >> 6;
  const float* wo = Wo + d * 1024 + h * 64;
  const float* mm = mem + hk * 64;
  float s = 0.f;
  #pragma unroll 8
  for (int v = 0; v < 64; ++v) s += wo[v] * mm[v];
  Weff[idx] = (__bf16)s;
}

// ================= 256x256 8-phase double-buffered MFMA core (C = A @ B^T) =================
// 512 threads = 8 waves (2 wave-rows x 4 wave-cols); per-wave 128x64 output; acc[8][4] f32x4.
// LDS 128KB: [buf0: A(32KB: h0,h1 16KB each) B(32KB)][buf1: same]. Halves:
//   A half h: local r in [0,128) -> global row (r>>6)*128 + (r&63) + h*64
//   B half h: local r in [0,128) -> global col (r>>5)*64  + (r&31) + h*32
// Swizzle: physical byte = logical byte ^ ((row&7)<<4)  (applied on pre-swizzled global src + reads)
__device__ __forceinline__ void gemm256_core(
    const __bf16* __restrict__ A, int lda,
    const __bf16* __restrict__ B, int ldb,
    int m0, int n0, int nt, char* sm, f32x4 acc[8][4]) {

  const int tid  = threadIdx.x;
  const int lane = tid & 63;
  const int wid  = tid >> 6;
  const int wr = wid >> 2, wc = wid & 3;
  const int lrow = lane & 15;
  const int sx  = (lrow & 7) << 4;
  const int kx0 = (((lane >> 4) << 4)      ) ^ sx;
  const int kx1 = (((lane >> 4) << 4) + 64 ) ^ sx;

  // staging: per round, thread covers 16B chunk; logical chunk pre-swizzled
  const int rr = tid >> 3;
  const int ce = (((tid & 7) ^ (rr & 7)) << 3);  // element offset within row
  const __bf16* pA = A + (size_t)(m0 + rr) * lda + ce;
  const __bf16* pB = B + (size_t)(n0 + ((rr >> 5) << 6) + (rr & 31)) * ldb + ce;
  char* dA = sm + tid * 16;
  char* dB = sm + 32768 + tid * 16;

#define BARX() asm volatile("s_barrier" ::: "memory")
#define VM4()  asm volatile("s_waitcnt vmcnt(4)" ::: "memory")
#define VM0()  asm volatile("s_waitcnt vmcnt(0)" ::: "memory")
#define NOVM
#define STAGE_A(buf, h, t_) do { int tt=(t_); if (tt>=nt) tt-=nt; int k0=tt<<6; \
    gload_lds16(pA + (size_t)((h)*64      )*lda + k0, dA + (buf)*65536 + (h)*16384); \
    gload_lds16(pA + (size_t)((h)*64 + 128)*lda + k0, dA + (buf)*65536 + (h)*16384 + 8192); } while(0)
#define STAGE_B(buf, h, t_) do { int tt=(t_); if (tt>=nt) tt-=nt; int k0=tt<<6; \
    gload_lds16(pB + (size_t)((h)*32      )*ldb + k0, dB + (buf)*65536 + (h)*16384); \
    gload_lds16(pB + (size_t)((h)*32 + 128)*ldb + k0, dB + (buf)*65536 + (h)*16384 + 8192); } while(0)

#define PHASE(buf, q, STAGES, DOVM) do { \
    const char* bb = sm + (buf)*65536; \
    const int mh = (q) >> 1, nh = (q) & 1; \
    bf16x8 av[4][2], bv[2][2]; \
    _Pragma("unroll") for (int m = 0; m < 4; ++m) { \
      const char* rp = bb + mh*16384 + (wr*64 + m*16 + lrow)*128; \
      av[m][0] = *(const bf16x8*)(rp + kx0); \
      av[m][1] = *(const bf16x8*)(rp + kx1); } \
    _Pragma("unroll") for (int n = 0; n < 2; ++n) { \
      const char* rp = bb + 32768 + nh*16384 + (wc*32 + n*16 + lrow)*128; \
      bv[n][0] = *(const bf16x8*)(rp + kx0); \
      bv[n][1] = *(const bf16x8*)(rp + kx1); } \
    STAGES; \
    BARX(); \
    __builtin_amdgcn_sched_barrier(0); \
    __builtin_amdgcn_s_setprio(1); \
    _Pragma("unroll") for (int m = 0; m < 4; ++m) \
      _Pragma("unroll") for (int n = 0; n < 2; ++n) { \
        acc[mh*4+m][nh*2+n] = __builtin_amdgcn_mfma_f32_16x16x32_bf16(av[m][0], bv[n][0], acc[mh*4+m][nh*2+n], 0, 0, 0); \
        acc[mh*4+m][nh*2+n] = __builtin_amdgcn_mfma_f32_16x16x32_bf16(av[m][1], bv[n][1], acc[mh*4+m][nh*2+n], 0, 0, 0); } \
    __builtin_amdgcn_s_setprio(0); \
    DOVM; \
    BARX(); } while (0)

  // prologue: tile0 full into buf0, tile1 A0,B0 into buf1
  STAGE_A(0, 0, 0); STAGE_B(0, 0, 0); STAGE_B(0, 1, 0); STAGE_A(0, 1, 0);
  STAGE_A(1, 0, 1); STAGE_B(1, 0, 1);
  VM4(); BARX();

  const int nit = nt >> 1;
  for (int it = 0; it < nit; ++it) {
    const int t = it << 1;
    PHASE(0, 0, STAGE_B(1, 1, t + 1), NOVM);
    PHASE(0, 1, STAGE_A(1, 1, t + 1), NOVM);
    PHASE(0, 2, STAGE_A(0, 0, t + 2), NOVM);
    PHASE(0, 3, STAGE_B(0, 0, t + 2), VM4());
    PHASE(1, 0, STAGE_B(0, 1, t + 2), NOVM);
    PHASE(1, 1, STAGE_A(0, 1, t + 2), NOVM);
    PHASE(1, 2, STAGE_A(1, 0, t + 3), NOVM);
    PHASE(1, 3, STAGE_B(1, 0, t + 3), VM4());
  }
  // drain before LDS is reused (next core call / epilogue)
  VM0(); BARX();
#undef PHASE
#undef STAGE_A
#undef STAGE_B
#undef BARX
#undef VM4
#undef VM0
#undef NOVM
}

// ---------------- GEMM 1: Y[16384 x 3072] = Xb @ [Wk;Wv;Wq]^T (bf16 out) ----------------
__global__ void __launch_bounds__(512, 2)
gemm_kvq_kernel(const __bf16* __restrict__ Xb, const __bf16* __restrict__ Wkvq,
                __bf16* __restrict__ Y) {
  __shared__ __attribute__((aligned(16))) char smem[131072];
  // XCD-aware swizzle: 768 = 8 XCDs x 96; consecutive local ids share bm (A-panel reuse)
  const int g = (blockIdx.x & 7) * 96 + (blockIdx.x >> 3);
  const int bm = g / 12, bn = g % 12;
  const int m0 = bm * 256, n0 = bn * 256;
  f32x4 acc[8][4] = {};
  gemm256_core(Xb, DIM, Wkvq, DIM, m0, n0, 32, smem, acc);

  const int tid = threadIdx.x, wid = tid >> 6, lane = tid & 63;
  const int wr = wid >> 2, wc = wid & 3;
  const int crow = (lane >> 4) << 2, ccol = lane & 15;
  #pragma unroll
  for (int f = 0; f < 8; ++f) {
    int row = m0 + wr * 128 + f * 16 + crow;
    #pragma unroll
    for (int n = 0; n < 4; ++n) {
      int col = n0 + wc * 64 + n * 16 + ccol;
      #pragma unroll
      for (int j = 0; j < 4; ++j)
        Y[(size_t)(row + j) * NKVQ + col] = (__bf16)acc[f][n][j];
    }
  }
}

// ---------------- GEMM 2: out = hidden + sigmoid(Xb@Wg^T) * (Q@Weff^T) ----------------
__global__ void __launch_bounds__(512, 2)
gemm_out_kernel(const __bf16* __restrict__ Xb, const __bf16* __restrict__ Wgb,
                const __bf16* __restrict__ Y, const __bf16* __restrict__ Weff,
                const float* __restrict__ hidden, float* __restrict__ out) {
  __shared__ __attribute__((aligned(16))) char smem[131072];
  const int g = (blockIdx.x & 7) * 64 + (blockIdx.x >> 3);
  const int bm = g >> 3, bn = g & 7;
  const int m0 = bm * 256, n0 = bn * 256;

  // gate GEMM (K=2048)
  f32x4 accg[8][4] = {};
  gemm256_core(Xb, DIM, Wgb, DIM, m0, n0, 32, smem, accg);
  // sigmoid + pack to bf16 (64 VGPRs) to free 128 f32 accumulators
  unsigned int gpk[8][4][2];
  #pragma unroll
  for (int f = 0; f < 8; ++f)
    #pragma unroll
    for (int n = 0; n < 4; ++n)
      #pragma unroll
      for (int j2 = 0; j2 < 2; ++j2) {
        float g0 = 1.0f / (1.0f + __expf(-accg[f][n][2 * j2]));
        float g1 = 1.0f / (1.0f + __expf(-accg[f][n][2 * j2 + 1]));
        gpk[f][n][j2] = (unsigned int)bfbits(g0) | ((unsigned int)bfbits(g1) << 16);
      }

  // readout GEMM (K=1024): A = q columns of Y
  f32x4 accp[8][4] = {};
  gemm256_core(Y + 2048, NKVQ, Weff, 1024, m0, n0, 16, smem, accp);

  const int tid = threadIdx.x, wid = tid >> 6, lane = tid & 63;
  const int wr = wid >> 2, wc = wid & 3;
  const int crow = (lane >> 4) << 2, ccol = lane & 15;
  #pragma unroll
  for (int f = 0; f < 8; ++f) {
    int row = m0 + wr * 128 + f * 16 + crow;
    #pragma unroll
    for (int n = 0; n < 4; ++n) {
      int col = n0 + wc * 64 + n * 16 + ccol;
      #pragma unroll
      for (int j = 0; j < 4; ++j) {
        size_t idx = (size_t)(row + j) * DIM + col;
        float gv = bff((unsigned short)(gpk[f][n][j >> 1] >> ((j & 1) * 16)));
        out[idx] = hidden[idx] + gv * accp[f][n][j];
      }
    }
  }
}

// ---------------- memory update partials: part[sp][h] += K_h^T V_h over 1024 tokens ----------------
__global__ void __launch_bounds__(256)
mem_update_kernel(const __bf16* __restrict__ Y, float* __restrict__ part) {
  const int h = blockIdx.x & 15, sp = blockIdx.x >> 4;
  __shared__ __attribute__((aligned(16))) __bf16 KT[64 * 32];  // [kdim][token]
  __shared__ __attribute__((aligned(16))) __bf16 VT[64 * 32];  // [vdim][token]
  const int tid = threadIdx.x, wid = tid >> 6, lane = tid & 63;
  const int lrow = lane & 15, lk = (lane >> 4) * 8;
  const __bf16* Kbase = Y + (size_t)sp * 1024 * NKVQ + h * 64;
  const __bf16* Vbase = Kbase + 1024;
  f32x4 acc[4] = {};
  const int t = tid >> 3, c8 = (tid & 7) * 8;
  for (int t0 = 0; t0 < 1024; t0 += 32) {
    __syncthreads();
    bf16x8 kv = *(const bf16x8*)(Kbase + (size_t)(t0 + t) * NKVQ + c8);
    bf16x8 vv = *(const bf16x8*)(Vbase + (size_t)(t0 + t) * NKVQ + c8);
    #pragma unroll
    for (int j = 0; j < 8; ++j) {
      KT[(c8 + j) * 32 + t] = kv[j];
      VT[(c8 + j) * 32 + t] = vv[j];
    }
    __syncthreads();
    bf16x8 af = *(const bf16x8*)(KT + (wid * 16 + lrow) * 32 + lk);
    #pragma unroll
    for (int n = 0; n < 4; ++n) {
      bf16x8 bf_ = *(const bf16x8*)(VT + (n * 16 + lrow) * 32 + lk);
      acc[n] = __builtin_amdgcn_mfma_f32_16x16x32_bf16(af, bf_, acc[n], 0, 0, 0);
    }
  }
  float* pp = part + ((size_t)sp * 16 + h) * 4096;
  const int crow = wid * 16 + (lane >> 4) * 4, ccol = lane & 15;
  #pragma unroll
  for (int n = 0; n < 4; ++n)
    #pragma unroll
    for (int r = 0; r < 4; ++r)
      pp[(crow + r) * 64 + n * 16 + ccol] = acc[n][r];
}

// ---------------- memory reduce: out = 0.99*mem + sum_sp part ----------------
__global__ void mem_reduce_kernel(const float* __restrict__ part, const float* __restrict__ mem,
                                  float* __restrict__ out) {
  int i = blockIdx.x * blockDim.x + threadIdx.x;  // 65536
  float s = 0.99f * mem[i];
  #pragma unroll
  for (int sp = 0; sp < 16; ++sp) s += part[sp * 65536 + i];
  out[i] = s;
}

extern "C" void kernel_launch(void* const* d_in, const int* in_sizes, int n_in,
                              void* d_out, int out_size, void* d_ws, size_t ws_size,
                              hipStream_t stream) {
  const float* hidden = (const float*)d_in[0];
  const float* memory = (const float*)d_in[1];
  const float* Wk = (const float*)d_in[2];
  const float* Wv = (const float*)d_in[3];
  const float* Wq = (const float*)d_in[4];
  const float* Wg = (const float*)d_in[5];
  const float* Wo = (const float*)d_in[6];
  float* out = (float*)d_out;
  float* mem_out = out + (size_t)TOKENS * DIM;

  char* ws = (char*)d_ws;
  __bf16* Xb   = (__bf16*)(ws);                    // 16384x2048  (67,108,864 B)
  __bf16* Wkvq = (__bf16*)(ws + 67108864);         // 3072x2048   (12,582,912 B)
  __bf16* Wgb  = (__bf16*)(ws + 79691776);         // 2048x2048   ( 8,388,608 B)
  __bf16* Weff = (__bf16*)(ws + 88080384);         // 2048x1024   ( 4,194,304 B)
  __bf16* Yb   = (__bf16*)(ws + 92274688);         // 16384x3072  (100,663,296 B)
  float*  part = (float*)(ws + 192937984);         // 16x16x64x64 ( 4,194,304 B)

  // casts
  cast8_kernel<<<16384, 256, 0, stream>>>(hidden, Xb, 4194304);
  cast8_kernel<<<1024, 256, 0, stream>>>(Wk, Wkvq, 262144);
  cast8_kernel<<<1024, 256, 0, stream>>>(Wv, Wkvq + 2097152, 262144);
  cast8_kernel<<<1024, 256, 0, stream>>>(Wq, Wkvq + 4194304, 262144);
  cast8_kernel<<<2048, 256, 0, stream>>>(Wg, Wgb, 524288);
  weff_kernel<<<8192, 256, 0, stream>>>(Wo, memory, Weff);

  // big GEMMs (256^2 8-phase)
  gemm_kvq_kernel<<<768, 512, 0, stream>>>(Xb, Wkvq, Yb);
  gemm_out_kernel<<<512, 512, 0, stream>>>(Xb, Wgb, Yb, Weff, hidden, out);

  // memory update
  mem_update_kernel<<<256, 256, 0, stream>>>(Yb, part);
  mem_reduce_kernel<<<256, 256, 0, stream>>>(part, memory, mem_out);
}

// Round 3
// 640.327 us; speedup vs baseline: 1.4701x; 1.4701x over previous
//
#include <hip/hip_runtime.h>
#include <hip/hip_bf16.h>

typedef __attribute__((ext_vector_type(4))) float f32x4;
typedef __bf16 bf16x8 __attribute__((ext_vector_type(8)));

#define TOKENS 16384
#define DIM    2048
#define NKVQ   3072

__device__ __forceinline__ void gload_lds16(const void* g, void* l) {
  __builtin_amdgcn_global_load_lds((const __attribute__((address_space(1))) void*)g,
                                   (__attribute__((address_space(3))) void*)l, 16, 0, 0);
}

__device__ __forceinline__ unsigned short bfbits(float x) {
  __bf16 b = (__bf16)x; return __builtin_bit_cast(unsigned short, b);
}
__device__ __forceinline__ float bff(unsigned short u) {
  return (float)__builtin_bit_cast(__bf16, u);
}

// ---------------- cast fp32 -> bf16, 8 elems/thread ----------------
__global__ void cast8_kernel(const float* __restrict__ src, __bf16* __restrict__ dst, int n8) {
  int i = blockIdx.x * blockDim.x + threadIdx.x;
  if (i >= n8) return;
  const float4* s = (const float4*)src;
  float4 a = s[2 * i], b = s[2 * i + 1];
  bf16x8 o;
  o[0] = (__bf16)a.x; o[1] = (__bf16)a.y; o[2] = (__bf16)a.z; o[3] = (__bf16)a.w;
  o[4] = (__bf16)b.x; o[5] = (__bf16)b.y; o[6] = (__bf16)b.z; o[7] = (__bf16)b.w;
  ((bf16x8*)dst)[i] = o;
}

// ---------------- Weff[d, h*64+k] = sum_v Wo[d, h*64+v] * mem[h,k,v] ----------------
__global__ void weff_kernel(const float* __restrict__ Wo, const float* __restrict__ mem,
                            __bf16* __restrict__ Weff) {
  int idx = blockIdx.x * blockDim.x + threadIdx.x;  // 2048*1024
  int d = idx >> 10, hk = idx & 1023, h = hk >> 6;
  const float* wo = Wo + d * 1024 + h * 64;
  const float* mm = mem + hk * 64;
  float s = 0.f;
  #pragma unroll 8
  for (int v = 0; v < 64; ++v) s += wo[v] * mm[v];
  Weff[idx] = (__bf16)s;
}

// ================= 256x256 8-phase double-buffered MFMA core (C = A @ B^T) =================
// (unchanged from round 2: correctness-verified, SQ_LDS_BANK_CONFLICT == 0)
__device__ __forceinline__ void gemm256_core(
    const __bf16* __restrict__ A, int lda,
    const __bf16* __restrict__ B, int ldb,
    int m0, int n0, int nt, char* sm, f32x4 acc[8][4]) {

  const int tid  = threadIdx.x;
  const int lane = tid & 63;
  const int wid  = tid >> 6;
  const int wr = wid >> 2, wc = wid & 3;
  const int lrow = lane & 15;
  const int sx  = (lrow & 7) << 4;
  const int kx0 = (((lane >> 4) << 4)      ) ^ sx;
  const int kx1 = (((lane >> 4) << 4) + 64 ) ^ sx;

  const int rr = tid >> 3;
  const int ce = (((tid & 7) ^ (rr & 7)) << 3);
  const __bf16* pA = A + (size_t)(m0 + rr) * lda + ce;
  const __bf16* pB = B + (size_t)(n0 + ((rr >> 5) << 6) + (rr & 31)) * ldb + ce;
  char* dA = sm + tid * 16;
  char* dB = sm + 32768 + tid * 16;

#define BARX() asm volatile("s_barrier" ::: "memory")
#define VM4()  asm volatile("s_waitcnt vmcnt(4)" ::: "memory")
#define VM0()  asm volatile("s_waitcnt vmcnt(0)" ::: "memory")
#define NOVM
#define STAGE_A(buf, h, t_) do { int tt=(t_); if (tt>=nt) tt-=nt; int k0=tt<<6; \
    gload_lds16(pA + (size_t)((h)*64      )*lda + k0, dA + (buf)*65536 + (h)*16384); \
    gload_lds16(pA + (size_t)((h)*64 + 128)*lda + k0, dA + (buf)*65536 + (h)*16384 + 8192); } while(0)
#define STAGE_B(buf, h, t_) do { int tt=(t_); if (tt>=nt) tt-=nt; int k0=tt<<6; \
    gload_lds16(pB + (size_t)((h)*32      )*ldb + k0, dB + (buf)*65536 + (h)*16384); \
    gload_lds16(pB + (size_t)((h)*32 + 128)*ldb + k0, dB + (buf)*65536 + (h)*16384 + 8192); } while(0)

#define PHASE(buf, q, STAGES, DOVM) do { \
    const char* bb = sm + (buf)*65536; \
    const int mh = (q) >> 1, nh = (q) & 1; \
    bf16x8 av[4][2], bv[2][2]; \
    _Pragma("unroll") for (int m = 0; m < 4; ++m) { \
      const char* rp = bb + mh*16384 + (wr*64 + m*16 + lrow)*128; \
      av[m][0] = *(const bf16x8*)(rp + kx0); \
      av[m][1] = *(const bf16x8*)(rp + kx1); } \
    _Pragma("unroll") for (int n = 0; n < 2; ++n) { \
      const char* rp = bb + 32768 + nh*16384 + (wc*32 + n*16 + lrow)*128; \
      bv[n][0] = *(const bf16x8*)(rp + kx0); \
      bv[n][1] = *(const bf16x8*)(rp + kx1); } \
    STAGES; \
    BARX(); \
    __builtin_amdgcn_sched_barrier(0); \
    __builtin_amdgcn_s_setprio(1); \
    _Pragma("unroll") for (int m = 0; m < 4; ++m) \
      _Pragma("unroll") for (int n = 0; n < 2; ++n) { \
        acc[mh*4+m][nh*2+n] = __builtin_amdgcn_mfma_f32_16x16x32_bf16(av[m][0], bv[n][0], acc[mh*4+m][nh*2+n], 0, 0, 0); \
        acc[mh*4+m][nh*2+n] = __builtin_amdgcn_mfma_f32_16x16x32_bf16(av[m][1], bv[n][1], acc[mh*4+m][nh*2+n], 0, 0, 0); } \
    __builtin_amdgcn_s_setprio(0); \
    DOVM; \
    BARX(); } while (0)

  STAGE_A(0, 0, 0); STAGE_B(0, 0, 0); STAGE_B(0, 1, 0); STAGE_A(0, 1, 0);
  STAGE_A(1, 0, 1); STAGE_B(1, 0, 1);
  VM4(); BARX();

  const int nit = nt >> 1;
  for (int it = 0; it < nit; ++it) {
    const int t = it << 1;
    PHASE(0, 0, STAGE_B(1, 1, t + 1), NOVM);
    PHASE(0, 1, STAGE_A(1, 1, t + 1), NOVM);
    PHASE(0, 2, STAGE_A(0, 0, t + 2), NOVM);
    PHASE(0, 3, STAGE_B(0, 0, t + 2), VM4());
    PHASE(1, 0, STAGE_B(0, 1, t + 2), NOVM);
    PHASE(1, 1, STAGE_A(0, 1, t + 2), NOVM);
    PHASE(1, 2, STAGE_A(1, 0, t + 3), NOVM);
    PHASE(1, 3, STAGE_B(1, 0, t + 3), VM4());
  }
  VM0(); BARX();
#undef PHASE
#undef STAGE_A
#undef STAGE_B
#undef BARX
#undef VM4
#undef VM0
#undef NOVM
}

// ============================ PATH A (ws >= 264 MB) ============================
// GEMM1: [Y | sigmoid-gate] = Xb @ [Wk;Wv;Wq;Wg]^T  (N = 5120)
__global__ void __launch_bounds__(512, 1)
gemm_fused_kernel(const __bf16* __restrict__ Xb, const __bf16* __restrict__ W1,
                  __bf16* __restrict__ Y, __bf16* __restrict__ Gb) {
  __shared__ __attribute__((aligned(16))) char smem[131072];
  const int g = (blockIdx.x & 7) * 160 + (blockIdx.x >> 3);  // 1280 = 8 x 160
  const int bm = g / 20, bn = g % 20;
  const int m0 = bm * 256, n0 = bn * 256;
  f32x4 acc[8][4] = {};
  gemm256_core(Xb, DIM, W1, DIM, m0, n0, 32, smem, acc);

  const int tid = threadIdx.x, wid = tid >> 6, lane = tid & 63;
  const int wr = wid >> 2, wc = wid & 3;
  const int crow = (lane >> 4) << 2, ccol = lane & 15;
  if (bn < 12) {
    #pragma unroll
    for (int f = 0; f < 8; ++f) {
      int row = m0 + wr * 128 + f * 16 + crow;
      #pragma unroll
      for (int n = 0; n < 4; ++n) {
        int col = n0 + wc * 64 + n * 16 + ccol;
        #pragma unroll
        for (int j = 0; j < 4; ++j)
          Y[(size_t)(row + j) * NKVQ + col] = (__bf16)acc[f][n][j];
      }
    }
  } else {
    const int c0 = n0 - 3072;
    #pragma unroll
    for (int f = 0; f < 8; ++f) {
      int row = m0 + wr * 128 + f * 16 + crow;
      #pragma unroll
      for (int n = 0; n < 4; ++n) {
        int col = c0 + wc * 64 + n * 16 + ccol;
        #pragma unroll
        for (int j = 0; j < 4; ++j) {
          float gv = 1.0f / (1.0f + __expf(-acc[f][n][j]));
          Gb[(size_t)(row + j) * DIM + col] = (__bf16)gv;
        }
      }
    }
  }
}

// GEMM2: out = hidden + Gb * (Q @ Weff^T)   (K = 1024)
__global__ void __launch_bounds__(512, 1)
gemm_read_kernel(const __bf16* __restrict__ Yq, const __bf16* __restrict__ Weff,
                 const __bf16* __restrict__ Gb, const float* __restrict__ hidden,
                 float* __restrict__ out) {
  __shared__ __attribute__((aligned(16))) char smem[131072];
  const int g = (blockIdx.x & 7) * 64 + (blockIdx.x >> 3);  // 512 = 8 x 64
  const int bm = g >> 3, bn = g & 7;
  const int m0 = bm * 256, n0 = bn * 256;
  f32x4 acc[8][4] = {};
  gemm256_core(Yq, NKVQ, Weff, 1024, m0, n0, 16, smem, acc);

  const int tid = threadIdx.x, wid = tid >> 6, lane = tid & 63;
  const int wr = wid >> 2, wc = wid & 3;
  const int crow = (lane >> 4) << 2, ccol = lane & 15;
  #pragma unroll
  for (int f = 0; f < 8; ++f) {
    int row = m0 + wr * 128 + f * 16 + crow;
    #pragma unroll
    for (int n = 0; n < 4; ++n) {
      int col = n0 + wc * 64 + n * 16 + ccol;
      #pragma unroll
      for (int j = 0; j < 4; ++j) {
        size_t idx = (size_t)(row + j) * DIM + col;
        out[idx] = hidden[idx] + (float)Gb[idx] * acc[f][n][j];
      }
    }
  }
}

// ============================ PATH B (small ws fallback) ============================
__global__ void __launch_bounds__(512, 1)
gemm_kvq_kernel(const __bf16* __restrict__ Xb, const __bf16* __restrict__ Wkvq,
                __bf16* __restrict__ Y) {
  __shared__ __attribute__((aligned(16))) char smem[131072];
  const int g = (blockIdx.x & 7) * 96 + (blockIdx.x >> 3);
  const int bm = g / 12, bn = g % 12;
  const int m0 = bm * 256, n0 = bn * 256;
  f32x4 acc[8][4] = {};
  gemm256_core(Xb, DIM, Wkvq, DIM, m0, n0, 32, smem, acc);
  const int tid = threadIdx.x, wid = tid >> 6, lane = tid & 63;
  const int wr = wid >> 2, wc = wid & 3;
  const int crow = (lane >> 4) << 2, ccol = lane & 15;
  #pragma unroll
  for (int f = 0; f < 8; ++f) {
    int row = m0 + wr * 128 + f * 16 + crow;
    #pragma unroll
    for (int n = 0; n < 4; ++n) {
      int col = n0 + wc * 64 + n * 16 + ccol;
      #pragma unroll
      for (int j = 0; j < 4; ++j)
        Y[(size_t)(row + j) * NKVQ + col] = (__bf16)acc[f][n][j];
    }
  }
}

__global__ void __launch_bounds__(512, 1)
gemm_out_kernel(const __bf16* __restrict__ Xb, const __bf16* __restrict__ Wgb,
                const __bf16* __restrict__ Y, const __bf16* __restrict__ Weff,
                const float* __restrict__ hidden, float* __restrict__ out) {
  __shared__ __attribute__((aligned(16))) char smem[131072];
  const int g = (blockIdx.x & 7) * 64 + (blockIdx.x >> 3);
  const int bm = g >> 3, bn = g & 7;
  const int m0 = bm * 256, n0 = bn * 256;

  f32x4 accg[8][4] = {};
  gemm256_core(Xb, DIM, Wgb, DIM, m0, n0, 32, smem, accg);
  unsigned int gpk[8][4][2];
  #pragma unroll
  for (int f = 0; f < 8; ++f)
    #pragma unroll
    for (int n = 0; n < 4; ++n)
      #pragma unroll
      for (int j2 = 0; j2 < 2; ++j2) {
        float g0 = 1.0f / (1.0f + __expf(-accg[f][n][2 * j2]));
        float g1 = 1.0f / (1.0f + __expf(-accg[f][n][2 * j2 + 1]));
        gpk[f][n][j2] = (unsigned int)bfbits(g0) | ((unsigned int)bfbits(g1) << 16);
      }

  f32x4 accp[8][4] = {};
  gemm256_core(Y + 2048, NKVQ, Weff, 1024, m0, n0, 16, smem, accp);

  const int tid = threadIdx.x, wid = tid >> 6, lane = tid & 63;
  const int wr = wid >> 2, wc = wid & 3;
  const int crow = (lane >> 4) << 2, ccol = lane & 15;
  #pragma unroll
  for (int f = 0; f < 8; ++f) {
    int row = m0 + wr * 128 + f * 16 + crow;
    #pragma unroll
    for (int n = 0; n < 4; ++n) {
      int col = n0 + wc * 64 + n * 16 + ccol;
      #pragma unroll
      for (int j = 0; j < 4; ++j) {
        size_t idx = (size_t)(row + j) * DIM + col;
        float gv = bff((unsigned short)(gpk[f][n][j >> 1] >> ((j & 1) * 16)));
        out[idx] = hidden[idx] + gv * accp[f][n][j];
      }
    }
  }
}

// ---------------- memory update partials ----------------
__global__ void __launch_bounds__(256)
mem_update_kernel(const __bf16* __restrict__ Y, float* __restrict__ part) {
  const int h = blockIdx.x & 15, sp = blockIdx.x >> 4;
  __shared__ __attribute__((aligned(16))) __bf16 KT[64 * 32];
  __shared__ __attribute__((aligned(16))) __bf16 VT[64 * 32];
  const int tid = threadIdx.x, wid = tid >> 6, lane = tid & 63;
  const int lrow = lane & 15, lk = (lane >> 4) * 8;
  const __bf16* Kbase = Y + (size_t)sp * 1024 * NKVQ + h * 64;
  const __bf16* Vbase = Kbase + 1024;
  f32x4 acc[4] = {};
  const int t = tid >> 3, c8 = (tid & 7) * 8;
  for (int t0 = 0; t0 < 1024; t0 += 32) {
    __syncthreads();
    bf16x8 kv = *(const bf16x8*)(Kbase + (size_t)(t0 + t) * NKVQ + c8);
    bf16x8 vv = *(const bf16x8*)(Vbase + (size_t)(t0 + t) * NKVQ + c8);
    #pragma unroll
    for (int j = 0; j < 8; ++j) {
      KT[(c8 + j) * 32 + t] = kv[j];
      VT[(c8 + j) * 32 + t] = vv[j];
    }
    __syncthreads();
    bf16x8 af = *(const bf16x8*)(KT + (wid * 16 + lrow) * 32 + lk);
    #pragma unroll
    for (int n = 0; n < 4; ++n) {
      bf16x8 bf_ = *(const bf16x8*)(VT + (n * 16 + lrow) * 32 + lk);
      acc[n] = __builtin_amdgcn_mfma_f32_16x16x32_bf16(af, bf_, acc[n], 0, 0, 0);
    }
  }
  float* pp = part + ((size_t)sp * 16 + h) * 4096;
  const int crow = wid * 16 + (lane >> 4) * 4, ccol = lane & 15;
  #pragma unroll
  for (int n = 0; n < 4; ++n)
    #pragma unroll
    for (int r = 0; r < 4; ++r)
      pp[(crow + r) * 64 + n * 16 + ccol] = acc[n][r];
}

__global__ void mem_reduce_kernel(const float* __restrict__ part, const float* __restrict__ mem,
                                  float* __restrict__ out) {
  int i = blockIdx.x * blockDim.x + threadIdx.x;
  float s = 0.99f * mem[i];
  #pragma unroll
  for (int sp = 0; sp < 16; ++sp) s += part[sp * 65536 + i];
  out[i] = s;
}

extern "C" void kernel_launch(void* const* d_in, const int* in_sizes, int n_in,
                              void* d_out, int out_size, void* d_ws, size_t ws_size,
                              hipStream_t stream) {
  const float* hidden = (const float*)d_in[0];
  const float* memory = (const float*)d_in[1];
  const float* Wk = (const float*)d_in[2];
  const float* Wv = (const float*)d_in[3];
  const float* Wq = (const float*)d_in[4];
  const float* Wg = (const float*)d_in[5];
  const float* Wo = (const float*)d_in[6];
  float* out = (float*)d_out;
  float* mem_out = out + (size_t)TOKENS * DIM;

  char* ws = (char*)d_ws;
  __bf16* Xb = (__bf16*)(ws);                      // 16384x2048 bf16 (67,108,864 B)

  cast8_kernel<<<16384, 256, 0, stream>>>(hidden, Xb, 4194304);

  if (ws_size >= 264241152ull) {
    // ---- PATH A ----
    __bf16* W1   = (__bf16*)(ws + 67108864);       // 5120x2048   (20,971,520 B)
    __bf16* Weff = (__bf16*)(ws + 88080384);       // 2048x1024   ( 4,194,304 B)
    __bf16* Yb   = (__bf16*)(ws + 92274688);       // 16384x3072  (100,663,296 B)
    __bf16* Gb   = (__bf16*)(ws + 192937984);      // 16384x2048  (67,108,864 B)
    float*  part = (float*)(ws + 260046848);       // 16x16x64x64 ( 4,194,304 B)

    cast8_kernel<<<1024, 256, 0, stream>>>(Wk, W1, 262144);
    cast8_kernel<<<1024, 256, 0, stream>>>(Wv, W1 + 2097152, 262144);
    cast8_kernel<<<1024, 256, 0, stream>>>(Wq, W1 + 4194304, 262144);
    cast8_kernel<<<2048, 256, 0, stream>>>(Wg, W1 + 6291456, 524288);
    weff_kernel<<<8192, 256, 0, stream>>>(Wo, memory, Weff);

    gemm_fused_kernel<<<1280, 512, 0, stream>>>(Xb, W1, Yb, Gb);
    gemm_read_kernel<<<512, 512, 0, stream>>>(Yb + 2048, Weff, Gb, hidden, out);

    mem_update_kernel<<<256, 256, 0, stream>>>(Yb, part);
    mem_reduce_kernel<<<256, 256, 0, stream>>>(part, memory, mem_out);
  } else {
    // ---- PATH B ----
    __bf16* Wkvq = (__bf16*)(ws + 67108864);       // 3072x2048   (12,582,912 B)
    __bf16* Wgb  = (__bf16*)(ws + 79691776);       // 2048x2048   ( 8,388,608 B)
    __bf16* Weff = (__bf16*)(ws + 88080384);       // 2048x1024   ( 4,194,304 B)
    __bf16* Yb   = (__bf16*)(ws + 92274688);       // 16384x3072  (100,663,296 B)
    float*  part = (float*)(ws + 192937984);       // ( 4,194,304 B)

    cast8_kernel<<<1024, 256, 0, stream>>>(Wk, Wkvq, 262144);
    cast8_kernel<<<1024, 256, 0, stream>>>(Wv, Wkvq + 2097152, 262144);
    cast8_kernel<<<1024, 256, 0, stream>>>(Wq, Wkvq + 4194304, 262144);
    cast8_kernel<<<2048, 256, 0, stream>>>(Wg, Wgb, 524288);
    weff_kernel<<<8192, 256, 0, stream>>>(Wo, memory, Weff);

    gemm_kvq_kernel<<<768, 512, 0, stream>>>(Xb, Wkvq, Yb);
    gemm_out_kernel<<<512, 512, 0, stream>>>(Xb, Wgb, Yb, Weff, hidden, out);

    mem_update_kernel<<<256, 256, 0, stream>>>(Yb, part);
    mem_reduce_kernel<<<256, 256, 0, stream>>>(part, memory, mem_out);
  }
}

// Round 4
// 637.894 us; speedup vs baseline: 1.4757x; 1.0038x over previous
//
#include <hip/hip_runtime.h>
#include <hip/hip_bf16.h>

typedef __attribute__((ext_vector_type(4))) float f32x4;
typedef __bf16 bf16x8 __attribute__((ext_vector_type(8)));

#define TOKENS 16384
#define DIM    2048
#define NKVQ   3072

__device__ __forceinline__ void gload_lds16(const void* g, void* l) {
  __builtin_amdgcn_global_load_lds((const __attribute__((address_space(1))) void*)g,
                                   (__attribute__((address_space(3))) void*)l, 16, 0, 0);
}

// ---------------- cast fp32 -> bf16, 8 elems/thread ----------------
__global__ void cast8_kernel(const float* __restrict__ src, __bf16* __restrict__ dst, int n8) {
  int i = blockIdx.x * blockDim.x + threadIdx.x;
  if (i >= n8) return;
  const float4* s = (const float4*)src;
  float4 a = s[2 * i], b = s[2 * i + 1];
  bf16x8 o;
  o[0] = (__bf16)a.x; o[1] = (__bf16)a.y; o[2] = (__bf16)a.z; o[3] = (__bf16)a.w;
  o[4] = (__bf16)b.x; o[5] = (__bf16)b.y; o[6] = (__bf16)b.z; o[7] = (__bf16)b.w;
  ((bf16x8*)dst)[i] = o;
}

// ---------------- Weff[d, h*64+k] = sum_v Wo[d, h*64+v] * mem[h,k,v] ----------------
__global__ void weff_kernel(const float* __restrict__ Wo, const float* __restrict__ mem,
                            __bf16* __restrict__ Weff) {
  int idx = blockIdx.x * blockDim.x + threadIdx.x;  // 2048*1024
  int d = idx >> 10, hk = idx & 1023, h = hk >> 6;
  const float* wo = Wo + d * 1024 + h * 64;
  const float* mm = mem + hk * 64;
  float s = 0.f;
  #pragma unroll 8
  for (int v = 0; v < 64; ++v) s += wo[v] * mm[v];
  Weff[idx] = (__bf16)s;
}

// ================= 256x256 MFMA core, BK=32, 4-buffer LDS ring (C = A @ B^T) =================
// 512 threads = 8 waves (2 wave-rows x 4 wave-cols); per-wave 128x64 output; acc[8][4] f32x4.
// LDS 128KB = 4 bufs x (A 16KB + B 16KB).  Tile: 256 rows x K=32, row-major 64B/row.
// Swizzle (16B units): phys = u ^ ((u>>3)&7)  -- involution; applied to global src (pre-swizzle)
// and to frag-read offsets; gload_lds dest stays linear.
// Phase p: read 12 frags of tile t (each frag ONCE) | stage tile t+3 | 32 MFMA | vmcnt(8) | barrier.
__device__ __forceinline__ void gemm256_core(
    const __bf16* __restrict__ A, int lda,
    const __bf16* __restrict__ B, int ldb,
    int m0, int n0, int nt, char* sm, f32x4 acc[8][4]) {

  const int tid = threadIdx.x, lane = tid & 63, wid = tid >> 6;
  const int wr = wid >> 2, wc = wid & 3;
  const int lrow = lane & 15, kc = lane >> 4;

  // frag read byte-offsets (swizzled)
  int offA[8], offB[4];
  #pragma unroll
  for (int m = 0; m < 8; ++m) {
    int u = (wr * 128 + m * 16 + lrow) * 4 + kc;
    offA[m] = (u ^ ((u >> 3) & 7)) << 4;
  }
  #pragma unroll
  for (int n = 0; n < 4; ++n) {
    int u = (wc * 64 + n * 16 + lrow) * 4 + kc;
    offB[n] = ((u ^ ((u >> 3) & 7)) << 4) + 16384;
  }

  // staging source pointers (pre-swizzled global so linear LDS dest lands swizzled)
  const __bf16* pSA[2]; const __bf16* pSB[2];
  #pragma unroll
  for (int s = 0; s < 2; ++s) {
    int U = s * 512 + tid;
    int u = U ^ ((U >> 3) & 7);
    pSA[s] = A + (size_t)(m0 + (u >> 2)) * lda + (u & 3) * 8;
    pSB[s] = B + (size_t)(n0 + (u >> 2)) * ldb + (u & 3) * 8;
  }

#define BARX() asm volatile("s_barrier" ::: "memory")
#define VM8()  asm volatile("s_waitcnt vmcnt(8)" ::: "memory")
#define VM4()  asm volatile("s_waitcnt vmcnt(4)" ::: "memory")
#define VM0()  asm volatile("s_waitcnt vmcnt(0)" ::: "memory")
#define NOVM
#define NOSTAGE
#define STAGE(bb, tt) do { \
    char* sA = sm + (bb) * 32768 + tid * 16; \
    gload_lds16(pSA[0] + (tt) * 32, sA); \
    gload_lds16(pSA[1] + (tt) * 32, sA + 8192); \
    gload_lds16(pSB[0] + (tt) * 32, sA + 16384); \
    gload_lds16(pSB[1] + (tt) * 32, sA + 24576); } while (0)

#define PHASE(bb, STAGES, WAITS) do { \
    const char* bA = sm + (bb) * 32768; \
    bf16x8 av[8], bv[4]; \
    _Pragma("unroll") for (int m = 0; m < 8; ++m) av[m] = *(const bf16x8*)(bA + offA[m]); \
    _Pragma("unroll") for (int n = 0; n < 4; ++n) bv[n] = *(const bf16x8*)(bA + offB[n]); \
    STAGES; \
    __builtin_amdgcn_sched_barrier(0); \
    __builtin_amdgcn_s_setprio(1); \
    _Pragma("unroll") for (int m = 0; m < 8; ++m) \
      _Pragma("unroll") for (int n = 0; n < 4; ++n) \
        acc[m][n] = __builtin_amdgcn_mfma_f32_16x16x32_bf16(av[m], bv[n], acc[m][n], 0, 0, 0); \
    __builtin_amdgcn_s_setprio(0); \
    WAITS; \
    BARX(); } while (0)

  // prologue: stage tiles 0,1,2 into bufs 0,1,2; wait tile0 (12 outstanding -> 8)
  STAGE(0, 0); STAGE(1, 1); STAGE(2, 2);
  VM8(); BARX();

  // main loop: nt % 4 == 0, nt >= 4. Each phase stages tile t+3, waits tile t+1.
  for (int i = 0; i < (nt >> 2) - 1; ++i) {
    const int t = i << 2;
    PHASE(0, STAGE(3, t + 3), VM8());
    PHASE(1, STAGE(0, t + 4), VM8());
    PHASE(2, STAGE(1, t + 5), VM8());
    PHASE(3, STAGE(2, t + 6), VM8());
  }
  // tail: t = nt-4 .. nt-1
  PHASE(0, STAGE(3, nt - 1), VM8());
  PHASE(1, NOSTAGE, VM4());
  PHASE(2, NOSTAGE, VM0());
  PHASE(3, NOSTAGE, NOVM);
#undef PHASE
#undef STAGE
#undef BARX
#undef VM8
#undef VM4
#undef VM0
#undef NOVM
#undef NOSTAGE
}

// ---------------- GEMM1: [Y | sigmoid-gate] = Xb @ [Wk;Wv;Wq;Wg]^T  (N = 5120) ----------------
__global__ void __launch_bounds__(512, 1)
gemm_fused_kernel(const __bf16* __restrict__ Xb, const __bf16* __restrict__ W1,
                  __bf16* __restrict__ Y, __bf16* __restrict__ Gb) {
  __shared__ __attribute__((aligned(16))) char smem[131072];
  const int g = (blockIdx.x & 7) * 160 + (blockIdx.x >> 3);  // 1280 = 8 x 160 (bijective)
  const int bm = g / 20, bn = g % 20;
  const int m0 = bm * 256, n0 = bn * 256;
  f32x4 acc[8][4] = {};
  gemm256_core(Xb, DIM, W1, DIM, m0, n0, 64, smem, acc);

  const int tid = threadIdx.x, wid = tid >> 6, lane = tid & 63;
  const int wr = wid >> 2, wc = wid & 3;
  const int crow = (lane >> 4) << 2, ccol = lane & 15;
  if (bn < 12) {
    #pragma unroll
    for (int f = 0; f < 8; ++f) {
      int row = m0 + wr * 128 + f * 16 + crow;
      #pragma unroll
      for (int n = 0; n < 4; ++n) {
        int col = n0 + wc * 64 + n * 16 + ccol;
        #pragma unroll
        for (int j = 0; j < 4; ++j)
          Y[(size_t)(row + j) * NKVQ + col] = (__bf16)acc[f][n][j];
      }
    }
  } else {
    const int c0 = n0 - 3072;
    #pragma unroll
    for (int f = 0; f < 8; ++f) {
      int row = m0 + wr * 128 + f * 16 + crow;
      #pragma unroll
      for (int n = 0; n < 4; ++n) {
        int col = c0 + wc * 64 + n * 16 + ccol;
        #pragma unroll
        for (int j = 0; j < 4; ++j) {
          float gv = 1.0f / (1.0f + __expf(-acc[f][n][j]));
          Gb[(size_t)(row + j) * DIM + col] = (__bf16)gv;
        }
      }
    }
  }
}

// ---------------- GEMM2: out = hidden + Gb * (Q @ Weff^T)   (K = 1024) ----------------
__global__ void __launch_bounds__(512, 1)
gemm_read_kernel(const __bf16* __restrict__ Yq, const __bf16* __restrict__ Weff,
                 const __bf16* __restrict__ Gb, const float* __restrict__ hidden,
                 float* __restrict__ out) {
  __shared__ __attribute__((aligned(16))) char smem[131072];
  const int g = (blockIdx.x & 7) * 64 + (blockIdx.x >> 3);  // 512 = 8 x 64 (bijective)
  const int bm = g >> 3, bn = g & 7;
  const int m0 = bm * 256, n0 = bn * 256;
  f32x4 acc[8][4] = {};
  gemm256_core(Yq, NKVQ, Weff, 1024, m0, n0, 32, smem, acc);

  const int tid = threadIdx.x, wid = tid >> 6, lane = tid & 63;
  const int wr = wid >> 2, wc = wid & 3;
  const int crow = (lane >> 4) << 2, ccol = lane & 15;
  #pragma unroll
  for (int f = 0; f < 8; ++f) {
    int row = m0 + wr * 128 + f * 16 + crow;
    #pragma unroll
    for (int n = 0; n < 4; ++n) {
      int col = n0 + wc * 64 + n * 16 + ccol;
      #pragma unroll
      for (int j = 0; j < 4; ++j) {
        size_t idx = (size_t)(row + j) * DIM + col;
        out[idx] = hidden[idx] + (float)Gb[idx] * acc[f][n][j];
      }
    }
  }
}

// ---------------- memory update partials: part[sp][h] += K_h^T V_h over 1024 tokens ----------------
__global__ void __launch_bounds__(256)
mem_update_kernel(const __bf16* __restrict__ Y, float* __restrict__ part) {
  const int h = blockIdx.x & 15, sp = blockIdx.x >> 4;
  __shared__ __attribute__((aligned(16))) __bf16 KT[64 * 32];
  __shared__ __attribute__((aligned(16))) __bf16 VT[64 * 32];
  const int tid = threadIdx.x, wid = tid >> 6, lane = tid & 63;
  const int lrow = lane & 15, lk = (lane >> 4) * 8;
  const __bf16* Kbase = Y + (size_t)sp * 1024 * NKVQ + h * 64;
  const __bf16* Vbase = Kbase + 1024;
  f32x4 acc[4] = {};
  const int t = tid >> 3, c8 = (tid & 7) * 8;
  for (int t0 = 0; t0 < 1024; t0 += 32) {
    __syncthreads();
    bf16x8 kv = *(const bf16x8*)(Kbase + (size_t)(t0 + t) * NKVQ + c8);
    bf16x8 vv = *(const bf16x8*)(Vbase + (size_t)(t0 + t) * NKVQ + c8);
    #pragma unroll
    for (int j = 0; j < 8; ++j) {
      KT[(c8 + j) * 32 + t] = kv[j];
      VT[(c8 + j) * 32 + t] = vv[j];
    }
    __syncthreads();
    bf16x8 af = *(const bf16x8*)(KT + (wid * 16 + lrow) * 32 + lk);
    #pragma unroll
    for (int n = 0; n < 4; ++n) {
      bf16x8 bf_ = *(const bf16x8*)(VT + (n * 16 + lrow) * 32 + lk);
      acc[n] = __builtin_amdgcn_mfma_f32_16x16x32_bf16(af, bf_, acc[n], 0, 0, 0);
    }
  }
  float* pp = part + ((size_t)sp * 16 + h) * 4096;
  const int crow = wid * 16 + (lane >> 4) * 4, ccol = lane & 15;
  #pragma unroll
  for (int n = 0; n < 4; ++n)
    #pragma unroll
    for (int r = 0; r < 4; ++r)
      pp[(crow + r) * 64 + n * 16 + ccol] = acc[n][r];
}

// ---------------- memory reduce: out = 0.99*mem + sum_sp part ----------------
__global__ void mem_reduce_kernel(const float* __restrict__ part, const float* __restrict__ mem,
                                  float* __restrict__ out) {
  int i = blockIdx.x * blockDim.x + threadIdx.x;
  float s = 0.99f * mem[i];
  #pragma unroll
  for (int sp = 0; sp < 16; ++sp) s += part[sp * 65536 + i];
  out[i] = s;
}

extern "C" void kernel_launch(void* const* d_in, const int* in_sizes, int n_in,
                              void* d_out, int out_size, void* d_ws, size_t ws_size,
                              hipStream_t stream) {
  const float* hidden = (const float*)d_in[0];
  const float* memory = (const float*)d_in[1];
  const float* Wk = (const float*)d_in[2];
  const float* Wv = (const float*)d_in[3];
  const float* Wq = (const float*)d_in[4];
  const float* Wg = (const float*)d_in[5];
  const float* Wo = (const float*)d_in[6];
  float* out = (float*)d_out;
  float* mem_out = out + (size_t)TOKENS * DIM;

  char* ws = (char*)d_ws;
  __bf16* Xb   = (__bf16*)(ws);                    // 16384x2048  (67,108,864 B)
  __bf16* W1   = (__bf16*)(ws + 67108864);         // 5120x2048   (20,971,520 B)
  __bf16* Weff = (__bf16*)(ws + 88080384);         // 2048x1024   ( 4,194,304 B)
  __bf16* Yb   = (__bf16*)(ws + 92274688);         // 16384x3072  (100,663,296 B)
  __bf16* Gb   = (__bf16*)(ws + 192937984);        // 16384x2048  (67,108,864 B)
  float*  part = (float*)(ws + 260046848);         // 16x16x64x64 ( 4,194,304 B)

  cast8_kernel<<<16384, 256, 0, stream>>>(hidden, Xb, 4194304);
  cast8_kernel<<<1024, 256, 0, stream>>>(Wk, W1, 262144);
  cast8_kernel<<<1024, 256, 0, stream>>>(Wv, W1 + 2097152, 262144);
  cast8_kernel<<<1024, 256, 0, stream>>>(Wq, W1 + 4194304, 262144);
  cast8_kernel<<<2048, 256, 0, stream>>>(Wg, W1 + 6291456, 524288);
  weff_kernel<<<8192, 256, 0, stream>>>(Wo, memory, Weff);

  gemm_fused_kernel<<<1280, 512, 0, stream>>>(Xb, W1, Yb, Gb);
  gemm_read_kernel<<<512, 512, 0, stream>>>(Yb + 2048, Weff, Gb, hidden, out);

  mem_update_kernel<<<256, 256, 0, stream>>>(Yb, part);
  mem_reduce_kernel<<<256, 256, 0, stream>>>(part, memory, mem_out);
}